// Round 4
// baseline (913.031 us; speedup 1.0000x reference)
//
#include <hip/hip_runtime.h>
#include <hip/hip_bf16.h>

#define UDIM    256
#define ODIM    128
#define ZDIM    1024
#define NSTEPS  48
#define BM      16
#define THREADS 1024
#define NBLOCKS 256   // 4096 / BM

// ws layout in ushort elements — now FP16 bits (11-bit mantissa: strictly
// more accurate than the previous bf16-hi weights, at the same byte count):
//   KR: [0,       393216)   64 tiles x 12 kc x 64 lanes x 8
//   D : [393216,  425984)   8 tiles x 8 kc x 64 lanes x 8
#define KR_FRAGS 393216
#define D_FRAGS  32768

// sA cols: [0,128)=x, [128,384)=h buf0, [384,640)=h buf1, pad to 664 (16B rows)
#define SA_W 664

typedef _Float16 f16x8 __attribute__((ext_vector_type(8)));
typedef float    f32x4 __attribute__((ext_vector_type(4)));

__device__ __forceinline__ ushort f2h_bits(float v) {
    _Float16 h = (_Float16)v;          // v_cvt_f16_f32, RNE
    return *reinterpret_cast<ushort*>(&h);
}
__device__ __forceinline__ float sigmoid_f(float x) {
    return 1.0f / (1.0f + __expf(-x));
}
__device__ __forceinline__ float tanh_f(float x) {
    return 1.0f - 2.0f / (__expf(2.0f * x) + 1.0f);
}

// ---- prep: pack weights into MFMA B-fragment order, fp16 (round-nearest) ----
__global__ void prep_weights(const float* __restrict__ kernel_w,   // [128,1024]
                             const float* __restrict__ rec_w,      // [256,1024]
                             const float* __restrict__ dense_w,    // [256,128]
                             ushort* __restrict__ ws) {
    int idx = blockIdx.x * blockDim.x + threadIdx.x;
    if (idx < KR_FRAGS) {
        int j  = idx & 7;
        int l  = (idx >> 3) & 63;
        int fc = idx >> 9;          // n*12 + kc
        int kc = fc % 12;
        int n  = fc / 12;
        int k   = kc * 32 + (l >> 4) * 8 + j;
        int col = n * 16 + (l & 15);
        float wv = (k < 128) ? kernel_w[k * ZDIM + col]
                             : rec_w[(k - 128) * ZDIM + col];
        ws[idx] = f2h_bits(wv);
    } else if (idx < KR_FRAGS + D_FRAGS) {
        int e  = idx - KR_FRAGS;
        int j  = e & 7;
        int l  = (e >> 3) & 63;
        int kc = (e >> 9) & 7;
        int n  = e >> 12;
        int k   = kc * 32 + (l >> 4) * 8 + j;
        int col = n * 16 + (l & 15);
        ws[KR_FRAGS + e] = f2h_bits(dense_w[k * ODIM + col]);
    }
}

// ---- main: BM=16 persistent LSTM, fp16 single-pass MFMA ----
// Wave w owns units 16w+cl, n-tiles n = w + 16g. One A-read per kc feeds 4 MFMAs.
// B-stream: 1-deep prefetch; kc==11 slot prefetches next step's kc0 so the
// stream keeps issuing across the gates/dense/barrier gap.
__global__ __launch_bounds__(THREADS, 4) void lstm_mfma_kernel(
    const float* __restrict__ last_input,  // [4096,128]
    const float* __restrict__ h0,          // [4096,256]
    const float* __restrict__ c0,          // [4096,256]
    const float* __restrict__ bias,        // [1024]
    const float* __restrict__ dense_b,     // [128]
    const ushort* __restrict__ wsro,
    float* __restrict__ out)               // [4096,48,128]
{
    const ushort* KR = wsro;

    __shared__ ushort sA[BM][SA_W];                  // fp16 bits
    __shared__ __align__(16) ushort sDw[D_FRAGS];    // dense weights, fp16 bits

    const int t  = threadIdx.x;
    const int w  = t >> 6;          // wave 0..15
    const int l  = t & 63;
    const int cl = l & 15;          // A row within tile / C col
    const int rg = l >> 4;          // C rows 4*rg..+4, k-group
    const int blockRow = blockIdx.x * BM;

    // ---- stage dense weights into LDS (once) ----
    for (int i = t * 8; i < D_FRAGS; i += THREADS * 8)
        *reinterpret_cast<f16x8*>(&sDw[i]) =
            *reinterpret_cast<const f16x8*>(&wsro[KR_FRAGS + i]);

    // ---- stage x0 (cols 0..127) and h0 (buf1: cols 384..639) ----
    for (int i = t; i < BM * ODIM; i += THREADS) {
        int r = i >> 7, c = i & 127;
        sA[r][c] = f2h_bits(last_input[(blockRow + r) * ODIM + c]);
    }
    for (int i = t; i < BM * UDIM; i += THREADS) {
        int r = i >> 8, c = i & 255;
        sA[r][384 + c] = f2h_bits(h0[(blockRow + r) * UDIM + c]);
    }

    // ---- per-lane state: units u = 16*w + cl, rows 4*rg + r ----
    const int unit = 16 * w + cl;
    float cstate[4];
    #pragma unroll
    for (int r = 0; r < 4; ++r)
        cstate[r] = c0[(blockRow + 4 * rg + r) * UDIM + unit];

    float bz[4];
    #pragma unroll
    for (int g = 0; g < 4; ++g)
        bz[g] = bias[256 * g + unit];
    const float db = dense_b[16 * (w & 7) + cl];

    // per-lane KR base (ushort elements); per-(g,kc) offsets fold into addressing
    const ushort* krbase = KR + (size_t)w * 6144 + (size_t)l * 8;

    // ---- prime the B-prefetch pipe with kc0 ----
    f16x8 bcur[4];
    #pragma unroll
    for (int g = 0; g < 4; ++g)
        bcur[g] = *reinterpret_cast<const f16x8*>(krbase + (size_t)g * 98304);

    __syncthreads();

    for (int s = 0; s < NSTEPS; ++s) {
        const int pw  = s & 1;
        const int hrd = 128 + (pw ^ 1) * 256;   // h read base (prev step)
        const int hwr = 128 + pw * 256;         // h write base (this step)

        // ======== GEMM1: Z[16,1024] = A[16,384] @ KR + bias (single-pass f16) ========
        f32x4 acc[4];
        #pragma unroll
        for (int g = 0; g < 4; ++g)
            acc[g] = (f32x4){bz[g], bz[g], bz[g], bz[g]};

        #pragma unroll
        for (int kc = 0; kc < 12; ++kc) {
            // prefetch next fragment set; kc==11 fetches NEXT STEP's kc0
            const int nk = (kc < 11) ? (kc + 1) : 0;
            f16x8 bnxt[4];
            #pragma unroll
            for (int g = 0; g < 4; ++g)
                bnxt[g] = *reinterpret_cast<const f16x8*>(krbase + (size_t)g * 98304 + (size_t)nk * 512);

            const int koff = (kc < 4) ? (kc * 32 + rg * 8)
                                      : (hrd + (kc - 4) * 32 + rg * 8);
            f16x8 a = *reinterpret_cast<const f16x8*>(&sA[cl][koff]);
            #pragma unroll
            for (int g = 0; g < 4; ++g)
                acc[g] = __builtin_amdgcn_mfma_f32_16x16x32_f16(a, bcur[g], acc[g], 0, 0, 0);
            #pragma unroll
            for (int g = 0; g < 4; ++g) bcur[g] = bnxt[g];
        }

        // ======== gates + state update; h_new into the OTHER buffer ========
        // No barrier needed before these writes: buffer hwr was last read in
        // GEMM1(s-1); every wave has passed the end-of-step barrier since.
        #pragma unroll
        for (int r = 0; r < 4; ++r) {
            float iv = sigmoid_f(acc[0][r]);
            float fv = sigmoid_f(acc[1][r]);
            float gv = tanh_f(acc[2][r]);
            float ov = sigmoid_f(acc[3][r]);
            float cn = fv * cstate[r] + iv * gv;
            cstate[r] = cn;
            float hv = ov * tanh_f(cn);
            sA[4 * rg + r][hwr + unit] = f2h_bits(hv);
        }
        __syncthreads();   // B2: h_new visible; also orders GEMM1 x-reads vs y-write

        // ======== dense: Y[16,128] = H[16,256] @ Wd + bd, relu (waves 0..7) ========
        if (w < 8) {
            f32x4 dacc = (f32x4){db, db, db, db};
            #pragma unroll
            for (int kc = 0; kc < 8; ++kc) {
                const int koff = hwr + kc * 32 + rg * 8;
                f16x8 ah = *reinterpret_cast<const f16x8*>(&sA[cl][koff]);
                f16x8 b  = *reinterpret_cast<const f16x8*>(&sDw[w * 4096 + kc * 512 + l * 8]);
                dacc = __builtin_amdgcn_mfma_f32_16x16x32_f16(ah, b, dacc, 0, 0, 0);
            }
            #pragma unroll
            for (int r = 0; r < 4; ++r) {
                float y = fmaxf(dacc[r], 0.0f);
                int row = 4 * rg + r;
                out[((size_t)(blockRow + row) * NSTEPS + s) * ODIM + 16 * w + cl] = y;
                sA[row][16 * w + cl] = f2h_bits(y);
            }
        }
        __syncthreads();   // B4: next-step x ready
    }
}

extern "C" void kernel_launch(void* const* d_in, const int* in_sizes, int n_in,
                              void* d_out, int out_size, void* d_ws, size_t ws_size,
                              hipStream_t stream) {
    const float* last_input = (const float*)d_in[0];
    const float* h0         = (const float*)d_in[1];
    const float* c0         = (const float*)d_in[2];
    const float* kernel_w   = (const float*)d_in[3];
    const float* rec_w      = (const float*)d_in[4];
    const float* bias       = (const float*)d_in[5];
    const float* dense_w    = (const float*)d_in[6];
    const float* dense_b    = (const float*)d_in[7];
    float* out  = (float*)d_out;
    ushort* ws  = (ushort*)d_ws;

    const int prep_total = KR_FRAGS + D_FRAGS;
    hipLaunchKernelGGL(prep_weights, dim3((prep_total + 255) / 256), dim3(256), 0, stream,
                       kernel_w, rec_w, dense_w, ws);
    hipLaunchKernelGGL(lstm_mfma_kernel, dim3(NBLOCKS), dim3(THREADS), 0, stream,
                       last_input, h0, c0, bias, dense_b, (const ushort*)ws, out);
}